// Round 10
// baseline (5434.590 us; speedup 1.0000x reference)
//
#include <hip/hip_runtime.h>
#include <hip/hip_bf16.h>

#define Vv 32000
#define Tz 256
#define Hz 256
#define HST 264   // LDS h row stride BYTES (fp8 256 + 8 pad -> odd 8B slots)

typedef __attribute__((ext_vector_type(8))) short short8;
typedef __attribute__((ext_vector_type(4))) float f32x4;

__device__ __forceinline__ float sigm(float x) { return 1.f / (1.f + __expf(-x)); }
__device__ __forceinline__ float tanh_(float x) {
    float e = __expf(2.f * x);
    return 1.f - 2.f / (e + 1.f);
}
__device__ __forceinline__ unsigned short f2bf(float x) {
    union { __hip_bfloat16 h; unsigned short u; } cv; cv.h = __float2bfloat16(x); return cv.u;
}
__device__ __forceinline__ float bf2f(unsigned short u) {
    union { unsigned u; float f; } cv; cv.u = ((unsigned)u) << 16; return cv.f;
}
__device__ __forceinline__ unsigned f2fp8(float x) {
    return ((unsigned)__builtin_amdgcn_cvt_pk_fp8_f32(x, x, 0, false)) & 0xffu;
}

// ---------- embedding gather -> XS bf16 [8192 rows = t*32+b][256]
__global__ __launch_bounds__(64) void k_embed(const int* __restrict__ inp,
    const float* __restrict__ emb, __hip_bfloat16* __restrict__ xs) {
    int row = blockIdx.x;
    int t = row >> 5, b = row & 31;
    const float* src = emb + (size_t)inp[b * Tz + t] * Hz;
    int tid = threadIdx.x;
    float4 v = *(const float4*)&src[tid * 4];
    __hip_bfloat16* dst = xs + (size_t)row * Hz + tid * 4;
    dst[0] = __float2bfloat16(v.x); dst[1] = __float2bfloat16(v.y);
    dst[2] = __float2bfloat16(v.z); dst[3] = __float2bfloat16(v.w);
}

// ---------- transpose+convert softmax_w [256][32000] f32 -> SWT [32000][256] bf16
__global__ __launch_bounds__(256) void k_swt(const float* __restrict__ sw,
                                             __hip_bfloat16* __restrict__ swt) {
    __shared__ float tile[64][65];
    int kt = blockIdx.x & 3, vt = blockIdx.x >> 2;
    int k0 = kt * 64, v0 = vt * 64, tid = threadIdx.x;
#pragma unroll
    for (int p = 0; p < 16; ++p) {
        int lin = p * 256 + tid;
        int kk = lin >> 6, vvi = lin & 63;
        tile[kk][vvi] = sw[(size_t)(k0 + kk) * Vv + v0 + vvi];
    }
    __syncthreads();
#pragma unroll
    for (int p = 0; p < 16; ++p) {
        int lin = p * 256 + tid;
        int vvi = lin >> 6, kk = lin & 63;
        swt[(size_t)(v0 + vvi) * 256 + k0 + kk] = __float2bfloat16(tile[kk][vvi]);
    }
}

// ---------- W [512 k][1024 zc] f32, zc = gate*256+hid, gi = hid*4+gate:
// k<256  (x-part) -> W?xG bf16 [1024 gi][256 k]
// k>=256 (h-part) -> W?hG fp8  [1024 gi][256 k]
__global__ __launch_bounds__(256) void k_wt(const float* __restrict__ W1,
    const float* __restrict__ W2, unsigned short* __restrict__ W1xG,
    unsigned short* __restrict__ W2xG, unsigned char* __restrict__ W1hG,
    unsigned char* __restrict__ W2hG)
{
    __shared__ float tile[64][65];
    int bid = blockIdx.x;              // 2 layers x 8 ktiles x 16 zctiles
    int layer = bid >> 7;
    int tl = bid & 127;
    int kt = tl & 7, zt = tl >> 3;
    int k0 = kt * 64, zc0 = zt * 64;
    int gate = zt >> 2, hid0 = (zt & 3) * 64;
    const float* W = layer ? W2 : W1;
    int tid = threadIdx.x;
#pragma unroll
    for (int p = 0; p < 16; ++p) {
        int lin = p * 256 + tid;
        int kk = lin >> 6, zz = lin & 63;
        tile[kk][zz] = W[(size_t)(k0 + kk) * 1024 + zc0 + zz];
    }
    __syncthreads();
    if (k0 < 256) {
        unsigned short* dst = layer ? W2xG : W1xG;
#pragma unroll
        for (int p = 0; p < 16; ++p) {
            int lin = p * 256 + tid;
            int zz = lin >> 6, kk = lin & 63;
            int gi = (hid0 + zz) * 4 + gate;
            dst[(size_t)gi * 256 + k0 + kk] = f2bf(tile[kk][zz]);
        }
    } else {
        unsigned char* dst = layer ? W2hG : W1hG;
        int kb = k0 - 256;
#pragma unroll
        for (int p = 0; p < 4; ++p) {
            int lin = p * 256 + tid;
            int zz = lin >> 4, kg = lin & 15;
            int gi = (hid0 + zz) * 4 + gate;
            unsigned r = (unsigned)__builtin_amdgcn_cvt_pk_fp8_f32(
                tile[kg * 4 + 0][zz], tile[kg * 4 + 1][zz], 0, false);
            r = (unsigned)__builtin_amdgcn_cvt_pk_fp8_f32(
                tile[kg * 4 + 2][zz], tile[kg * 4 + 3][zz], (int)r, true);
            *(unsigned*)&dst[(size_t)gi * 256 + kb + kg * 4] = r;
        }
    }
}

// ---------- bulk x-GEMM: A[8192][256] bf16 @ Bg[1024 gi][256]^T + bias -> outG [8192][1024] bf16
__global__ __launch_bounds__(256) void k_xw(const __hip_bfloat16* __restrict__ Abf,
    const unsigned short* __restrict__ Bg, const float* __restrict__ bv,
    unsigned short* __restrict__ outG)
{
    __shared__ __align__(16) unsigned short As[128 * 64];
    __shared__ __align__(16) unsigned short Bs[128 * 64];
    int tid = threadIdx.x;
    size_t r0 = (size_t)blockIdx.x * 128;
    size_t c0 = (size_t)blockIdx.y * 128;
    int l = tid & 63, w = tid >> 6, lr = l & 15, lk = l >> 4;
    f32x4 acc[2][8];
#pragma unroll
    for (int m = 0; m < 2; ++m)
#pragma unroll
        for (int f = 0; f < 8; ++f) acc[m][f] = (f32x4){0.f, 0.f, 0.f, 0.f};
    const unsigned short* A = (const unsigned short*)Abf;
    for (int kt = 0; kt < 4; ++kt) {
#pragma unroll
        for (int i = 0; i < 4; ++i) {
            int fi = i * 256 + tid;
            int row = fi >> 3, seg = fi & 7;
            int dseg = seg ^ (row & 7);
            *(short8*)&As[row * 64 + dseg * 8] =
                *(const short8*)&A[(r0 + row) * 256 + kt * 64 + seg * 8];
            *(short8*)&Bs[row * 64 + dseg * 8] =
                *(const short8*)&Bg[((size_t)c0 + row) * 256 + kt * 64 + seg * 8];
        }
        __syncthreads();
#pragma unroll
        for (int ks = 0; ks < 2; ++ks) {
            short8 a[2];
#pragma unroll
            for (int m = 0; m < 2; ++m) {
                int row = w * 32 + m * 16 + lr;
                a[m] = *(const short8*)&As[row * 64 + ((ks * 4 + lk) ^ (row & 7)) * 8];
            }
#pragma unroll
            for (int f = 0; f < 8; ++f) {
                int row = f * 16 + lr;
                short8 bfr = *(const short8*)&Bs[row * 64 + ((ks * 4 + lk) ^ (row & 7)) * 8];
#pragma unroll
                for (int m = 0; m < 2; ++m)
                    acc[m][f] = __builtin_amdgcn_mfma_f32_16x16x32_bf16(a[m], bfr, acc[m][f], 0, 0, 0);
            }
        }
        __syncthreads();
    }
#pragma unroll
    for (int f = 0; f < 8; ++f) {
        int gi = (int)c0 + f * 16 + lr;
        float bb = bv[(gi & 3) * 256 + (gi >> 2)];
#pragma unroll
        for (int m = 0; m < 2; ++m)
#pragma unroll
            for (int j = 0; j < 4; ++j)
                outG[(r0 + w * 32 + m * 16 + lk * 4 + j) * 1024 + gi] =
                    f2bf(acc[m][f][j] + bb);
    }
}

// ---------- single-CU layer sweep: one block, 512 threads, W_h fp8 in VGPRs (128/lane),
// c in VGPRs, h in LDS double buffer. ONE __syncthreads per step, no atomics/flags.
// layer=0: hout rows t*32+b (feeds z2x GEMM). layer=1: hout rows b*256+t (logits layout).
__global__ __launch_bounds__(512, 2) void k_sweep(
    const int layer,
    const unsigned short* __restrict__ zxG,    // [8192][1024] bf16, rows t*32+b, bias folded
    const unsigned char* __restrict__ WhG,     // [1024 gi][256 k] fp8
    unsigned short* __restrict__ hout)         // [8192][256] bf16
{
    __shared__ __align__(16) unsigned char hl[2][32 * HST];
    int tid = threadIdx.x;
    int w = tid >> 6, l = tid & 63, lr = l & 15, lk = l >> 4;

    // weights -> VGPRs: 8 hbl x 8 kc x 8B = 128 VGPR/lane; covers gi = (w*8+hbl)*16+lr
    long Wf[8][8];
#pragma unroll
    for (int hbl = 0; hbl < 8; ++hbl)
#pragma unroll
        for (int kc = 0; kc < 8; ++kc)
            Wf[hbl][kc] = *(const long*)&WhG[(size_t)((w * 8 + hbl) * 16 + lr) * 256 + kc * 32 + lk * 8];

    float c_[8][2];
#pragma unroll
    for (int i = 0; i < 8; ++i) { c_[i][0] = 0.f; c_[i][1] = 0.f; }

    for (int u = tid; u < 2 * 32 * HST / 4; u += 512) ((unsigned*)hl)[u] = 0u;  // h(-1)=0
    __syncthreads();

    for (int t = 0; t < 256; ++t) {
        int cur = t & 1;
        // z addend: 4 bf16 gate-quad per (hbl,bh), issued early (consumed post-MFMA)
        uint2 ad[8][2];
#pragma unroll
        for (int hbl = 0; hbl < 8; ++hbl)
#pragma unroll
            for (int bh = 0; bh < 2; ++bh)
                ad[hbl][bh] = *(const uint2*)&zxG[((size_t)t * 32 + bh * 16 + lr) * 1024 + (w * 8 + hbl) * 16 + lk * 4];

#pragma unroll
        for (int bh = 0; bh < 2; ++bh) {
            f32x4 acc[8];
#pragma unroll
            for (int hbl = 0; hbl < 8; ++hbl) acc[hbl] = (f32x4){0.f, 0.f, 0.f, 0.f};
#pragma unroll
            for (int kc = 0; kc < 8; ++kc) {
                long hf = *(const long*)&hl[cur][(bh * 16 + lr) * HST + kc * 32 + lk * 8];
#pragma unroll
                for (int hbl = 0; hbl < 8; ++hbl)
                    acc[hbl] = __builtin_amdgcn_mfma_f32_16x16x32_fp8_fp8(Wf[hbl][kc], hf, acc[hbl], 0, 0, 0);
            }
            // gates; D row = gi_local = lk*4+j (j = gate), col = batch = lr
#pragma unroll
            for (int hbl = 0; hbl < 8; ++hbl) {
                float zi = acc[hbl][0] + bf2f((unsigned short)(ad[hbl][bh].x & 0xffff));
                float zj = acc[hbl][1] + bf2f((unsigned short)(ad[hbl][bh].x >> 16));
                float zf = acc[hbl][2] + bf2f((unsigned short)(ad[hbl][bh].y & 0xffff));
                float zo = acc[hbl][3] + bf2f((unsigned short)(ad[hbl][bh].y >> 16));
                float cn = c_[hbl][bh] * sigm(zf + 1.f) + sigm(zi) * tanh_(zj);
                c_[hbl][bh] = cn;
                float hv = tanh_(cn) * sigm(zo);
                // pack fp8 quad across lk lanes -> LDS next buffer
                unsigned x = f2fp8(hv) << (lk * 8);
                x |= __shfl_xor(x, 16); x |= __shfl_xor(x, 32);
                // pack bf16 pairs across lk parity -> global publish
                unsigned y = ((unsigned)f2bf(hv)) << ((lk & 1) * 16);
                y |= __shfl_xor(y, 16);
                int br = bh * 16 + lr, hb = (w * 8 + hbl) * 4;
                if (lk == 0)
                    *(unsigned*)&hl[cur ^ 1][br * HST + hb] = x;
                if ((lk & 1) == 0) {
                    size_t row = layer ? ((size_t)br * 256 + t) : ((size_t)t * 32 + br);
                    *(unsigned*)&hout[row * 256 + hb + lk] = y;
                }
            }
        }
        __syncthreads();   // hl[cur^1] complete for step t+1
    }
}

// ---------- logits GEMM: 128x128 tile, BK=64, XOR-swizzled LDS, streaming sum-of-exp
__global__ __launch_bounds__(256) void k_gemm(const __hip_bfloat16* __restrict__ Abf,
    const __hip_bfloat16* __restrict__ Bbf, const float* __restrict__ sb,
    float* __restrict__ row_sum)
{
    __shared__ __align__(16) unsigned short As[128 * 64];
    __shared__ __align__(16) unsigned short Bs[128 * 64];
    int tid = threadIdx.x;
    size_t r0 = (size_t)blockIdx.x * 128;
    size_t c0 = (size_t)blockIdx.y * 128;
    int l = tid & 63, w = tid >> 6, lr = l & 15, lk = l >> 4;

    f32x4 acc[2][8];
#pragma unroll
    for (int m = 0; m < 2; ++m)
#pragma unroll
        for (int f = 0; f < 8; ++f) acc[m][f] = (f32x4){0.f, 0.f, 0.f, 0.f};

    const unsigned short* A = (const unsigned short*)Abf;
    const unsigned short* B = (const unsigned short*)Bbf;

    for (int kt = 0; kt < 4; ++kt) {
#pragma unroll
        for (int i = 0; i < 4; ++i) {
            int fi = i * 256 + tid;
            int row = fi >> 3, seg = fi & 7;
            int dseg = seg ^ (row & 7);
            *(short8*)&As[row * 64 + dseg * 8] =
                *(const short8*)&A[(r0 + row) * 256 + kt * 64 + seg * 8];
            *(short8*)&Bs[row * 64 + dseg * 8] =
                *(const short8*)&B[(c0 + row) * 256 + kt * 64 + seg * 8];
        }
        __syncthreads();
#pragma unroll
        for (int ks = 0; ks < 2; ++ks) {
            short8 a[2];
#pragma unroll
            for (int m = 0; m < 2; ++m) {
                int row = w * 32 + m * 16 + lr;
                a[m] = *(const short8*)&As[row * 64 + ((ks * 4 + lk) ^ (row & 7)) * 8];
            }
#pragma unroll
            for (int f = 0; f < 8; ++f) {
                int row = f * 16 + lr;
                short8 bfr = *(const short8*)&Bs[row * 64 + ((ks * 4 + lk) ^ (row & 7)) * 8];
#pragma unroll
                for (int m = 0; m < 2; ++m)
                    acc[m][f] = __builtin_amdgcn_mfma_f32_16x16x32_bf16(a[m], bfr, acc[m][f], 0, 0, 0);
            }
        }
        __syncthreads();
    }

    float sums[2][4] = {{0.f,0.f,0.f,0.f},{0.f,0.f,0.f,0.f}};
#pragma unroll
    for (int f = 0; f < 8; ++f) {
        float sbv = sb[c0 + f * 16 + lr];
#pragma unroll
        for (int m = 0; m < 2; ++m)
#pragma unroll
            for (int j = 0; j < 4; ++j) sums[m][j] += __expf(acc[m][f][j] + sbv);
    }
#pragma unroll
    for (int msk = 1; msk <= 8; msk <<= 1)
#pragma unroll
        for (int m = 0; m < 2; ++m)
#pragma unroll
            for (int j = 0; j < 4; ++j) sums[m][j] += __shfl_xor(sums[m][j], msk);
    if (lr == 0) {
#pragma unroll
        for (int m = 0; m < 2; ++m)
#pragma unroll
            for (int j = 0; j < 4; ++j)
                atomicAdd(&row_sum[r0 + w * 32 + m * 16 + lk * 4 + j], sums[m][j]);
    }
}

// ---------- per-row loss: log(sum_exp) - target logit
__global__ __launch_bounds__(256) void k_loss(const __hip_bfloat16* __restrict__ houtB,
    const __hip_bfloat16* __restrict__ swt, const float* __restrict__ sb,
    const int* __restrict__ tgts, const float* __restrict__ row_sum,
    float* __restrict__ out)
{
    int r = blockIdx.x * 256 + threadIdx.x;
    int tg = tgts[r];
    const unsigned short* h = (const unsigned short*)houtB + (size_t)r * Hz;
    const unsigned short* wp = (const unsigned short*)swt + (size_t)tg * Hz;
    float acc = 0.f;
#pragma unroll 4
    for (int k8 = 0; k8 < 32; ++k8) {
        short8 hv = *(const short8*)&h[k8 * 8];
        short8 wv = *(const short8*)&wp[k8 * 8];
#pragma unroll
        for (int e = 0; e < 8; ++e)
            acc += bf2f((unsigned short)hv[e]) * bf2f((unsigned short)wv[e]);
    }
    float loss = logf(row_sum[r]) - (acc + sb[tg]);
#pragma unroll
    for (int m = 1; m < 64; m <<= 1) loss += __shfl_xor(loss, m);
    __shared__ float red[4];
    int l = threadIdx.x & 63, wvv = threadIdx.x >> 6;
    if (l == 0) red[wvv] = loss;
    __syncthreads();
    if (threadIdx.x == 0) {
        float s = red[0] + red[1] + red[2] + red[3];
        atomicAdd(out, s * (1.f / 8192.f));
    }
}

extern "C" void kernel_launch(void* const* d_in, const int* in_sizes, int n_in,
                              void* d_out, int out_size, void* d_ws, size_t ws_size,
                              hipStream_t stream)
{
    const int*   inp = (const int*)d_in[0];
    const int*   tgt = (const int*)d_in[1];
    const float* emb = (const float*)d_in[2];
    const float* W1  = (const float*)d_in[3];
    const float* b1  = (const float*)d_in[4];
    const float* W2  = (const float*)d_in[5];
    const float* b2  = (const float*)d_in[6];
    const float* sw  = (const float*)d_in[7];
    const float* sb  = (const float*)d_in[8];
    float* out = (float*)d_out;

    char* ws = (char*)d_ws;
    size_t off = 0;
    __hip_bfloat16* SWT  = (__hip_bfloat16*)(ws + off); off += (size_t)Vv * Hz * 2;       // 16,384,000
    __hip_bfloat16* XS   = (__hip_bfloat16*)(ws + off); off += (size_t)8192 * Hz * 2;     //  4,194,304
    unsigned short* W1xG = (unsigned short*)(ws + off); off += (size_t)1024 * 256 * 2;    //    524,288
    unsigned short* W2xG = (unsigned short*)(ws + off); off += (size_t)1024 * 256 * 2;    //    524,288
    unsigned char*  W1hG = (unsigned char*)(ws + off);  off += (size_t)1024 * 256;        //    262,144
    unsigned char*  W2hG = (unsigned char*)(ws + off);  off += (size_t)1024 * 256;        //    262,144
    unsigned short* Z1   = (unsigned short*)(ws + off); off += (size_t)8192 * 1024 * 2;   // 16,777,216 (reused as Z2)
    unsigned short* H1P  = (unsigned short*)(ws + off); off += (size_t)8192 * Hz * 2;     //  4,194,304
    unsigned short* HoutB= (unsigned short*)(ws + off); off += (size_t)8192 * Hz * 2;     //  4,194,304
    float* row_sum       = (float*)(ws + off);          off += 8192 * 4;                  //     32,768
    // total ~47.4 MiB

    hipMemsetAsync(row_sum, 0, 8192 * 4, stream);
    hipMemsetAsync(out, 0, sizeof(float), stream);

    k_embed<<<8192, 64, 0, stream>>>(inp, emb, XS);
    k_wt<<<256, 256, 0, stream>>>(W1, W2, W1xG, W2xG, W1hG, W2hG);
    k_swt<<<2000, 256, 0, stream>>>(sw, SWT);
    // z1x = XS @ W1x + b1 (full GPU)
    k_xw<<<dim3(64, 8), 256, 0, stream>>>(XS, W1xG, b1, Z1);
    // layer-1 sweep (1 CU, no cross-CU sync)
    k_sweep<<<1, 512, 0, stream>>>(0, Z1, W1hG, H1P);
    // z2x = H1 @ W2x + b2 (full GPU; Z1 buffer reused)
    k_xw<<<dim3(64, 8), 256, 0, stream>>>((const __hip_bfloat16*)H1P, W2xG, b2, Z1);
    // layer-2 sweep (1 CU)
    k_sweep<<<1, 512, 0, stream>>>(1, Z1, W2hG, HoutB);
    k_gemm<<<dim3(64, 250), 256, 0, stream>>>((const __hip_bfloat16*)HoutB, SWT, sb, row_sum);
    k_loss<<<32, 256, 0, stream>>>((const __hip_bfloat16*)HoutB, SWT, sb, tgt, row_sum, out);
}

// Round 11
// 2447.802 us; speedup vs baseline: 2.2202x; 2.2202x over previous
//
#include <hip/hip_runtime.h>
#include <hip/hip_bf16.h>

#define Vv 32000
#define Tz 256
#define Hz 256

typedef __attribute__((ext_vector_type(8))) short short8;
typedef __attribute__((ext_vector_type(4))) float f32x4;

__device__ __forceinline__ float sigm(float x) { return 1.f / (1.f + __expf(-x)); }
__device__ __forceinline__ float tanh_(float x) {
    float e = __expf(2.f * x);
    return 1.f - 2.f / (e + 1.f);
}
__device__ __forceinline__ unsigned short f2bf(float x) {
    union { __hip_bfloat16 h; unsigned short u; } cv; cv.h = __float2bfloat16(x); return cv.u;
}
__device__ __forceinline__ float bf2f(unsigned short u) {
    union { unsigned u; float f; } cv; cv.u = ((unsigned)u) << 16; return cv.f;
}
__device__ __forceinline__ unsigned f2fp8(float x) {
    return ((unsigned)__builtin_amdgcn_cvt_pk_fp8_f32(x, x, 0, false)) & 0xffu;
}

// ---------- embedding gather -> XS bf16 [8192 rows = t*32+b][256]
__global__ __launch_bounds__(64) void k_embed(const int* __restrict__ inp,
    const float* __restrict__ emb, __hip_bfloat16* __restrict__ xs) {
    int row = blockIdx.x;
    int t = row >> 5, b = row & 31;
    const float* src = emb + (size_t)inp[b * Tz + t] * Hz;
    int tid = threadIdx.x;
    float4 v = *(const float4*)&src[tid * 4];
    __hip_bfloat16* dst = xs + (size_t)row * Hz + tid * 4;
    dst[0] = __float2bfloat16(v.x); dst[1] = __float2bfloat16(v.y);
    dst[2] = __float2bfloat16(v.z); dst[3] = __float2bfloat16(v.w);
}

// ---------- W [512 k][1024 zc] f32, zc = gate*256+hid, gi = hid*4+gate:
// k<256  (x-part) -> W?xG bf16 [1024 gi][256 k]
// k>=256 (h-part) -> W?hG fp8  [1024 gi][256 k]
__global__ __launch_bounds__(256) void k_wt(const float* __restrict__ W1,
    const float* __restrict__ W2, unsigned short* __restrict__ W1xG,
    unsigned short* __restrict__ W2xG, unsigned char* __restrict__ W1hG,
    unsigned char* __restrict__ W2hG)
{
    __shared__ float tile[64][65];
    int bid = blockIdx.x;              // 2 layers x 8 ktiles x 16 zctiles
    int layer = bid >> 7;
    int tl = bid & 127;
    int kt = tl & 7, zt = tl >> 3;
    int k0 = kt * 64, zc0 = zt * 64;
    int gate = zt >> 2, hid0 = (zt & 3) * 64;
    const float* W = layer ? W2 : W1;
    int tid = threadIdx.x;
#pragma unroll
    for (int p = 0; p < 16; ++p) {
        int lin = p * 256 + tid;
        int kk = lin >> 6, zz = lin & 63;
        tile[kk][zz] = W[(size_t)(k0 + kk) * 1024 + zc0 + zz];
    }
    __syncthreads();
    if (k0 < 256) {
        unsigned short* dst = layer ? W2xG : W1xG;
#pragma unroll
        for (int p = 0; p < 16; ++p) {
            int lin = p * 256 + tid;
            int zz = lin >> 6, kk = lin & 63;
            int gi = (hid0 + zz) * 4 + gate;
            dst[(size_t)gi * 256 + k0 + kk] = f2bf(tile[kk][zz]);
        }
    } else {
        unsigned char* dst = layer ? W2hG : W1hG;
        int kb = k0 - 256;
#pragma unroll
        for (int p = 0; p < 4; ++p) {
            int lin = p * 256 + tid;
            int zz = lin >> 4, kg = lin & 15;
            int gi = (hid0 + zz) * 4 + gate;
            unsigned r = (unsigned)__builtin_amdgcn_cvt_pk_fp8_f32(
                tile[kg * 4 + 0][zz], tile[kg * 4 + 1][zz], 0, false);
            r = (unsigned)__builtin_amdgcn_cvt_pk_fp8_f32(
                tile[kg * 4 + 2][zz], tile[kg * 4 + 3][zz], (int)r, true);
            *(unsigned*)&dst[(size_t)gi * 256 + kb + kg * 4] = r;
        }
    }
}

// ---------- bulk x-GEMM: A[8192][256] bf16 @ Bg[1024 gi][256]^T + bias -> outG [8192][1024] bf16
__global__ __launch_bounds__(256) void k_xw(const __hip_bfloat16* __restrict__ Abf,
    const unsigned short* __restrict__ Bg, const float* __restrict__ bv,
    unsigned short* __restrict__ outG)
{
    __shared__ __align__(16) unsigned short As[128 * 64];
    __shared__ __align__(16) unsigned short Bs[128 * 64];
    int tid = threadIdx.x;
    size_t r0 = (size_t)blockIdx.x * 128;
    size_t c0 = (size_t)blockIdx.y * 128;
    int l = tid & 63, w = tid >> 6, lr = l & 15, lk = l >> 4;
    f32x4 acc[2][8];
#pragma unroll
    for (int m = 0; m < 2; ++m)
#pragma unroll
        for (int f = 0; f < 8; ++f) acc[m][f] = (f32x4){0.f, 0.f, 0.f, 0.f};
    const unsigned short* A = (const unsigned short*)Abf;
    for (int kt = 0; kt < 4; ++kt) {
#pragma unroll
        for (int i = 0; i < 4; ++i) {
            int fi = i * 256 + tid;
            int row = fi >> 3, seg = fi & 7;
            int dseg = seg ^ (row & 7);
            *(short8*)&As[row * 64 + dseg * 8] =
                *(const short8*)&A[(r0 + row) * 256 + kt * 64 + seg * 8];
            *(short8*)&Bs[row * 64 + dseg * 8] =
                *(const short8*)&Bg[((size_t)c0 + row) * 256 + kt * 64 + seg * 8];
        }
        __syncthreads();
#pragma unroll
        for (int ks = 0; ks < 2; ++ks) {
            short8 a[2];
#pragma unroll
            for (int m = 0; m < 2; ++m) {
                int row = w * 32 + m * 16 + lr;
                a[m] = *(const short8*)&As[row * 64 + ((ks * 4 + lk) ^ (row & 7)) * 8];
            }
#pragma unroll
            for (int f = 0; f < 8; ++f) {
                int row = f * 16 + lr;
                short8 bfr = *(const short8*)&Bs[row * 64 + ((ks * 4 + lk) ^ (row & 7)) * 8];
#pragma unroll
                for (int m = 0; m < 2; ++m)
                    acc[m][f] = __builtin_amdgcn_mfma_f32_16x16x32_bf16(a[m], bfr, acc[m][f], 0, 0, 0);
            }
        }
        __syncthreads();
    }
#pragma unroll
    for (int f = 0; f < 8; ++f) {
        int gi = (int)c0 + f * 16 + lr;
        float bb = bv[(gi & 3) * 256 + (gi >> 2)];
#pragma unroll
        for (int m = 0; m < 2; ++m)
#pragma unroll
            for (int j = 0; j < 4; ++j)
                outG[(r0 + w * 32 + m * 16 + lk * 4 + j) * 1024 + gi] =
                    f2bf(acc[m][f][j] + bb);
    }
}

// ---------- batch-split layer sweep: block b owns batch element b, all 256 steps,
// full W_h fp8 in VGPRs (128/lane, PINNED vs rematerialization). No cross-CU sync ever.
// blocks >=32 (only in the layer-0 launch): folded softmax_w transpose.
__global__ __launch_bounds__(512, 2) void k_sweep(
    const int layer,
    const unsigned short* __restrict__ zxG,    // [8192][1024] bf16, rows t*32+b, bias folded
    const unsigned char* __restrict__ WhG,     // [1024 gi][256 k] fp8
    unsigned short* __restrict__ hout,         // layer0: rows t*32+b ; layer1: rows b*256+t
    const float* __restrict__ sw, __hip_bfloat16* __restrict__ swt)
{
    __shared__ __align__(16) unsigned char hl[2][256];     // fp8 h double buffer
    __shared__ __align__(16) unsigned short zb[2][1024];   // bf16 z row double buffer
    __shared__ __align__(16) unsigned short hb[2][256];    // bf16 h staging
    __shared__ float tile[64][65];                         // transpose path
    int bid = blockIdx.x, tid = threadIdx.x;

    if (bid >= 32) {       // folded softmax_w transpose (224 workers, sweep-0 launch only)
        int idx = bid - 32;
        for (int tl = idx; tl < 2000; tl += 224) {
            int kt = tl & 3, vt = tl >> 2;
            int k0 = kt * 64, v0 = vt * 64;
#pragma unroll
            for (int pp = 0; pp < 8; ++pp) {
                int lin = pp * 512 + tid;
                int kk = lin >> 6, vv = lin & 63;
                tile[kk][vv] = sw[(size_t)(k0 + kk) * Vv + v0 + vv];
            }
            __syncthreads();
#pragma unroll
            for (int pp = 0; pp < 8; ++pp) {
                int lin = pp * 512 + tid;
                int vv = lin >> 6, kk = lin & 63;
                swt[(size_t)(v0 + vv) * 256 + k0 + kk] = __float2bfloat16(tile[kk][vv]);
            }
            __syncthreads();
        }
        return;
    }

    int b = bid;                       // batch element
    int w = tid >> 6, l = tid & 63, lr = l & 15, lk = l >> 4;

    // ---- full W_h -> VGPRs: 64 longs = 128 VGPR/lane, pinned opaque (no remat)
    long Wf[8][8];
#pragma unroll
    for (int hbl = 0; hbl < 8; ++hbl)
#pragma unroll
        for (int kc = 0; kc < 8; ++kc) {
            Wf[hbl][kc] = *(const long*)&WhG[(size_t)((w * 8 + hbl) * 16 + lr) * 256 + kc * 32 + lk * 8];
            asm volatile("" : "+v"(Wf[hbl][kc]));
        }

    float c_[8];
#pragma unroll
    for (int i = 0; i < 8; ++i) c_[i] = 0.f;

    // init: h(-1)=0; z(0) row
    if (tid < 64) ((unsigned*)hl[0])[tid] = 0u;
    ((unsigned*)zb[0])[tid] = ((const unsigned*)&zxG[(size_t)b * 1024])[tid];
    __syncthreads();

    for (int t = 0; t < 256; ++t) {
        int cur = t & 1;
        // prefetch z(t+1): 512 lanes x 4B = 2KB contiguous
        unsigned zr = 0u;
        if (t < 255)
            zr = *(const unsigned*)&zxG[((size_t)(t + 1) * 32 + b) * 1024 + tid * 2];

        // MFMA: 64 per wave; B operand = h vector broadcast (only D col 0 meaningful,
        // but all cols duplicate since all lanes load identical h) — gates identical per lr.
        f32x4 acc[8];
#pragma unroll
        for (int hbl = 0; hbl < 8; ++hbl) acc[hbl] = (f32x4){0.f, 0.f, 0.f, 0.f};
#pragma unroll
        for (int kc = 0; kc < 8; ++kc) {
            long hf = *(const long*)&hl[cur][kc * 32 + lk * 8];
#pragma unroll
            for (int hbl = 0; hbl < 8; ++hbl)
                acc[hbl] = __builtin_amdgcn_mfma_f32_16x16x32_fp8_fp8(Wf[hbl][kc], hf, acc[hbl], 0, 0, 0);
        }

        // stash z(t+1) into the other z buffer (not read until after this step's barrier)
        if (t < 255) *(unsigned*)&zb[cur ^ 1][tid * 2] = zr;

        // gates: D row = lk*4+j -> gi = tile*16+lk*4+j; gate-grouped => j IS the gate,
        // hid = tile*4+lk. All lr lanes compute duplicates; lr==0 writes.
#pragma unroll
        for (int hbl = 0; hbl < 8; ++hbl) {
            int gi0 = (w * 8 + hbl) * 16 + lk * 4;
            uint2 zv = *(const uint2*)&zb[cur][gi0];
            float zi = acc[hbl][0] + bf2f((unsigned short)(zv.x & 0xffff));
            float zj = acc[hbl][1] + bf2f((unsigned short)(zv.x >> 16));
            float zf = acc[hbl][2] + bf2f((unsigned short)(zv.y & 0xffff));
            float zo = acc[hbl][3] + bf2f((unsigned short)(zv.y >> 16));
            float cn = c_[hbl] * sigm(zf + 1.f) + sigm(zi) * tanh_(zj);
            c_[hbl] = cn;
            float hv = tanh_(cn) * sigm(zo);
            if (lr == 0) {
                int hid = (w * 8 + hbl) * 4 + lk;
                hl[cur ^ 1][hid] = (unsigned char)f2fp8(hv);
                hb[cur ^ 1][hid] = f2bf(hv);
            }
        }
        __syncthreads();   // hl/hb[cur^1] and zb[cur^1] complete; all reads of [cur] done

        // publish h(t) coalesced (512B)
        if (tid < 32) {
            uint4 v = *(const uint4*)&hb[cur ^ 1][tid * 8];
            size_t row = layer ? ((size_t)b * 256 + t) : ((size_t)t * 32 + b);
            *(uint4*)&hout[row * 256 + tid * 8] = v;
        }
    }
}

// ---------- logits GEMM: 128x128 tile, BK=64, XOR-swizzled LDS, streaming sum-of-exp
__global__ __launch_bounds__(256) void k_gemm(const __hip_bfloat16* __restrict__ Abf,
    const __hip_bfloat16* __restrict__ Bbf, const float* __restrict__ sb,
    float* __restrict__ row_sum)
{
    __shared__ __align__(16) unsigned short As[128 * 64];
    __shared__ __align__(16) unsigned short Bs[128 * 64];
    int tid = threadIdx.x;
    size_t r0 = (size_t)blockIdx.x * 128;
    size_t c0 = (size_t)blockIdx.y * 128;
    int l = tid & 63, w = tid >> 6, lr = l & 15, lk = l >> 4;

    f32x4 acc[2][8];
#pragma unroll
    for (int m = 0; m < 2; ++m)
#pragma unroll
        for (int f = 0; f < 8; ++f) acc[m][f] = (f32x4){0.f, 0.f, 0.f, 0.f};

    const unsigned short* A = (const unsigned short*)Abf;
    const unsigned short* B = (const unsigned short*)Bbf;

    for (int kt = 0; kt < 4; ++kt) {
#pragma unroll
        for (int i = 0; i < 4; ++i) {
            int fi = i * 256 + tid;
            int row = fi >> 3, seg = fi & 7;
            int dseg = seg ^ (row & 7);
            *(short8*)&As[row * 64 + dseg * 8] =
                *(const short8*)&A[(r0 + row) * 256 + kt * 64 + seg * 8];
            *(short8*)&Bs[row * 64 + dseg * 8] =
                *(const short8*)&B[(c0 + row) * 256 + kt * 64 + seg * 8];
        }
        __syncthreads();
#pragma unroll
        for (int ks = 0; ks < 2; ++ks) {
            short8 a[2];
#pragma unroll
            for (int m = 0; m < 2; ++m) {
                int row = w * 32 + m * 16 + lr;
                a[m] = *(const short8*)&As[row * 64 + ((ks * 4 + lk) ^ (row & 7)) * 8];
            }
#pragma unroll
            for (int f = 0; f < 8; ++f) {
                int row = f * 16 + lr;
                short8 bfr = *(const short8*)&Bs[row * 64 + ((ks * 4 + lk) ^ (row & 7)) * 8];
#pragma unroll
                for (int m = 0; m < 2; ++m)
                    acc[m][f] = __builtin_amdgcn_mfma_f32_16x16x32_bf16(a[m], bfr, acc[m][f], 0, 0, 0);
            }
        }
        __syncthreads();
    }

    float sums[2][4] = {{0.f,0.f,0.f,0.f},{0.f,0.f,0.f,0.f}};
#pragma unroll
    for (int f = 0; f < 8; ++f) {
        float sbv = sb[c0 + f * 16 + lr];
#pragma unroll
        for (int m = 0; m < 2; ++m)
#pragma unroll
            for (int j = 0; j < 4; ++j) sums[m][j] += __expf(acc[m][f][j] + sbv);
    }
#pragma unroll
    for (int msk = 1; msk <= 8; msk <<= 1)
#pragma unroll
        for (int m = 0; m < 2; ++m)
#pragma unroll
            for (int j = 0; j < 4; ++j) sums[m][j] += __shfl_xor(sums[m][j], msk);
    if (lr == 0) {
#pragma unroll
        for (int m = 0; m < 2; ++m)
#pragma unroll
            for (int j = 0; j < 4; ++j)
                atomicAdd(&row_sum[r0 + w * 32 + m * 16 + lk * 4 + j], sums[m][j]);
    }
}

// ---------- per-row loss: log(sum_exp) - target logit
__global__ __launch_bounds__(256) void k_loss(const __hip_bfloat16* __restrict__ houtB,
    const __hip_bfloat16* __restrict__ swt, const float* __restrict__ sb,
    const int* __restrict__ tgts, const float* __restrict__ row_sum,
    float* __restrict__ out)
{
    int r = blockIdx.x * 256 + threadIdx.x;
    int tg = tgts[r];
    const unsigned short* h = (const unsigned short*)houtB + (size_t)r * Hz;
    const unsigned short* wp = (const unsigned short*)swt + (size_t)tg * Hz;
    float acc = 0.f;
#pragma unroll 4
    for (int k8 = 0; k8 < 32; ++k8) {
        short8 hv = *(const short8*)&h[k8 * 8];
        short8 wv = *(const short8*)&wp[k8 * 8];
#pragma unroll
        for (int e = 0; e < 8; ++e)
            acc += bf2f((unsigned short)hv[e]) * bf2f((unsigned short)wv[e]);
    }
    float loss = logf(row_sum[r]) - (acc + sb[tg]);
#pragma unroll
    for (int m = 1; m < 64; m <<= 1) loss += __shfl_xor(loss, m);
    __shared__ float red[4];
    int l = threadIdx.x & 63, wvv = threadIdx.x >> 6;
    if (l == 0) red[wvv] = loss;
    __syncthreads();
    if (threadIdx.x == 0) {
        float s = red[0] + red[1] + red[2] + red[3];
        atomicAdd(out, s * (1.f / 8192.f));
    }
}

extern "C" void kernel_launch(void* const* d_in, const int* in_sizes, int n_in,
                              void* d_out, int out_size, void* d_ws, size_t ws_size,
                              hipStream_t stream)
{
    const int*   inp = (const int*)d_in[0];
    const int*   tgt = (const int*)d_in[1];
    const float* emb = (const float*)d_in[2];
    const float* W1  = (const float*)d_in[3];
    const float* b1  = (const float*)d_in[4];
    const float* W2  = (const float*)d_in[5];
    const float* b2  = (const float*)d_in[6];
    const float* sw  = (const float*)d_in[7];
    const float* sb  = (const float*)d_in[8];
    float* out = (float*)d_out;

    char* ws = (char*)d_ws;
    size_t off = 0;
    __hip_bfloat16* SWT  = (__hip_bfloat16*)(ws + off); off += (size_t)Vv * Hz * 2;       // 16,384,000
    __hip_bfloat16* XS   = (__hip_bfloat16*)(ws + off); off += (size_t)8192 * Hz * 2;     //  4,194,304
    unsigned short* W1xG = (unsigned short*)(ws + off); off += (size_t)1024 * 256 * 2;    //    524,288
    unsigned short* W2xG = (unsigned short*)(ws + off); off += (size_t)1024 * 256 * 2;    //    524,288
    unsigned char*  W1hG = (unsigned char*)(ws + off);  off += (size_t)1024 * 256;        //    262,144
    unsigned char*  W2hG = (unsigned char*)(ws + off);  off += (size_t)1024 * 256;        //    262,144
    unsigned short* Z1   = (unsigned short*)(ws + off); off += (size_t)8192 * 1024 * 2;   // 16,777,216 (z1 then z2)
    unsigned short* H1P  = (unsigned short*)(ws + off); off += (size_t)8192 * Hz * 2;     //  4,194,304
    unsigned short* HoutB= (unsigned short*)(ws + off); off += (size_t)8192 * Hz * 2;     //  4,194,304
    float* row_sum       = (float*)(ws + off);          off += 8192 * 4;                  //     32,768
    // total ~47.4 MiB

    hipMemsetAsync(row_sum, 0, 8192 * 4, stream);
    hipMemsetAsync(out, 0, sizeof(float), stream);

    k_embed<<<8192, 64, 0, stream>>>(inp, emb, XS);
    k_wt<<<256, 256, 0, stream>>>(W1, W2, W1xG, W2xG, W1hG, W2hG);
    // z1 = XS @ W1x + b1 (full GPU)
    k_xw<<<dim3(64, 8), 256, 0, stream>>>(XS, W1xG, b1, Z1);
    // layer-1 sweep: 32 batch-split blocks + 224 folded-transpose blocks
    k_sweep<<<256, 512, 0, stream>>>(0, Z1, W1hG, H1P, sw, SWT);
    // z2 = H1 @ W2x + b2 (full GPU; Z1 reused)
    k_xw<<<dim3(64, 8), 256, 0, stream>>>((const __hip_bfloat16*)H1P, W2xG, b2, Z1);
    // layer-2 sweep: 32 blocks only
    k_sweep<<<32, 512, 0, stream>>>(1, Z1, W2hG, HoutB, sw, SWT);
    k_gemm<<<dim3(64, 250), 256, 0, stream>>>((const __hip_bfloat16*)HoutB, SWT, sb, row_sum);
    k_loss<<<32, 256, 0, stream>>>((const __hip_bfloat16*)HoutB, SWT, sb, tgt, row_sum, out);
}